// Round 5
// baseline (260.891 us; speedup 1.0000x reference)
//
#include <hip/hip_runtime.h>
#include <cmath>

#define HW 3136          // 56*56
#define NF 64            // BB*LL frames
#define NBLK3 896        // NF * 14 row-tiles (conv blocks)

typedef __attribute__((ext_vector_type(8))) short short8;
typedef __attribute__((ext_vector_type(4))) float float4a;

__device__ __forceinline__ unsigned short f2bf(float f) {
    unsigned int u = __float_as_uint(f);
    u += 0x7fffu + ((u >> 16) & 1u);   // RNE
    return (unsigned short)(u >> 16);
}
__device__ __forceinline__ float bf2f(unsigned short u) {
    return __uint_as_float(((unsigned int)u) << 16);
}

// cos/sin of -2*pi*k/8 for k=0..7
__device__ __constant__ float TW8C[8] = {1.f, 0.70710678f, 0.f, -0.70710678f, -1.f, -0.70710678f, 0.f, 0.70710678f};
__device__ __constant__ float TW8S[8] = {0.f, -0.70710678f, -1.f, -0.70710678f, 0.f, 0.70710678f, 1.f, 0.70710678f};

// ---------------------------------------------------------------------------
// Kernel 0: pack DFT matrix (blocks 0..63) + repack conv_w (blocks 64..207).
// Ffix[p][t][ks][lane][j]: Astack_p[t*16+(lane&15)][ks*32+(lane>>4)*8+j]
//   Astack_0 = [Fr | -Fi] (K=112 pad 128), Astack_1 = [Fi | Fr]
// Wp[kk][o][i] bf16 from conv_w[o][i][kk] fp32.
// ---------------------------------------------------------------------------
__global__ __launch_bounds__(256)
void pack_kernel(const float* __restrict__ cw,
                 unsigned short* __restrict__ Ffix,
                 unsigned short* __restrict__ Wp) {
    if (blockIdx.x < 64) {
        int idx = blockIdx.x * 256 + threadIdx.x;    // 16384
        int j    = idx & 7;
        int lane = (idx >> 3) & 63;
        int ks   = (idx >> 9) & 3;
        int t    = (idx >> 11) & 3;
        int p    = (idx >> 13) & 1;
        int mn = t * 16 + (lane & 15);
        int k  = ks * 32 + (lane >> 4) * 8 + j;
        float val = 0.f;
        if (mn < 56 && k < 112) {
            int kk = (k < 56) ? k : k - 56;
            int prod = (mn * kk) % 56;
            float ang = -6.2831853071795864f * (float)prod / 56.0f;
            float cr = cosf(ang);
            float ci = sinf(ang);
            float first  = (p == 0) ? cr : ci;
            float second = (p == 0) ? -ci : cr;
            val = (k < 56) ? first : second;
        }
        Ffix[idx] = f2bf(val);
    } else {
        int idx = (blockIdx.x - 64) * 256 + threadIdx.x;
        if (idx < 36864) {
            int i  = idx & 63;
            int o  = (idx >> 6) & 63;
            int kk = idx >> 12;
            Wp[idx] = f2bf(cw[(o * 64 + i) * 9 + kk]);
        }
    }
}

// ---------------------------------------------------------------------------
// Kernel 1a: temporal DFT for ALL lp=0..4 in one streaming pass.
// Block = (bc, half-plane chunk). Reads x[b,:,c,chunk] once, writes bf16
// planes Tg[(bc*5+lp)*2+ri][3136]  (h-major; Tg lives in d_out scratch).
// ---------------------------------------------------------------------------
__global__ __launch_bounds__(256)
void tdft_kernel(const float* __restrict__ x, unsigned short* __restrict__ Tg) {
    const int chunk = blockIdx.x & 1;
    const int bc    = blockIdx.x >> 1;     // 512
    const int c     = bc & 63;
    const int b     = bc >> 6;
    const int tid   = threadIdx.x;

    const float* xb = x + ((size_t)(b * 512 + c)) * HW;   // stride per l: 64*HW

    for (int g = chunk * 392 + tid; g < (chunk + 1) * 392; g += 256) {
        float4 v[8];
        #pragma unroll
        for (int l = 0; l < 8; ++l)
            v[l] = *(const float4*)(xb + (size_t)l * 64 * HW + g * 4);
        #pragma unroll
        for (int lp = 0; lp < 5; ++lp) {
            float re[4] = {0.f, 0.f, 0.f, 0.f}, im[4] = {0.f, 0.f, 0.f, 0.f};
            #pragma unroll
            for (int l = 0; l < 8; ++l) {
                float tr = TW8C[(l * lp) & 7], ti = TW8S[(l * lp) & 7];
                re[0] += v[l].x * tr; im[0] += v[l].x * ti;
                re[1] += v[l].y * tr; im[1] += v[l].y * ti;
                re[2] += v[l].z * tr; im[2] += v[l].z * ti;
                re[3] += v[l].w * tr; im[3] += v[l].w * ti;
            }
            ushort4 ur, ui;
            ur.x = f2bf(re[0]); ur.y = f2bf(re[1]); ur.z = f2bf(re[2]); ur.w = f2bf(re[3]);
            ui.x = f2bf(im[0]); ui.y = f2bf(im[1]); ui.z = f2bf(im[2]); ui.w = f2bf(im[3]);
            size_t base = ((size_t)(bc * 5 + lp) * 2) * HW + g * 4;
            *(ushort4*)(Tg + base)      = ur;
            *(ushort4*)(Tg + base + HW) = ui;
        }
    }
}

// ---------------------------------------------------------------------------
// Kernel 1b: 2D DFT via MFMA + fused |G|-weighted pooling.
// One block per (bc, lp). LDS = Tb + Ub only (30.5 KB) -> 4-5 blocks/CU.
//  Phase B: U = F*T   (A = Ffix global, B = Tb LDS)
//  Phase C: G = U*F   (A = Ub LDS,  B = Ffix global)
//  Epilogue: |G|-weighted sums vs global x[lp] (+ flipped vs x[8-lp])
// ---------------------------------------------------------------------------
__global__ __launch_bounds__(256)
void fft2_kernel(const float* __restrict__ x,
                 const unsigned short* __restrict__ Tg,
                 const unsigned short* __restrict__ Ffix,
                 float* __restrict__ pooled) {
    const int bid = blockIdx.x;          // 2560 = bc*5 + lp
    const int lp  = bid % 5;
    const int bc  = bid / 5;
    const int c   = bc & 63;
    const int b   = bc >> 6;
    const int tid  = threadIdx.x;
    const int lane = tid & 63;
    const int wv   = tid >> 6;
    const int n    = lane & 15;
    const int q    = lane >> 4;

    __shared__ unsigned short Tb[56 * 136];
    __shared__ unsigned short Ub[56 * 136];
    __shared__ float red[16];

    // zero K-pad slots 112..135 (A/B frags read them; Ffix rows there are 0,
    // but keep them finite-clean)
    for (int t = tid; t < 1344; t += 256) {
        int row = t / 24, k = 112 + t % 24;
        Tb[row * 136 + k] = 0;
        Ub[row * 136 + k] = 0;
    }
    // stage Tb transposed: Tg plane [ri][h*56+w] -> Tb[w][ri*56+h]
    const unsigned short* tg = Tg + (size_t)bid * 2 * HW;
    for (int t = tid; t < 1568; t += 256) {       // 2 ri x 784 ushort4-groups
        int ri = t / 784, g = t - ri * 784;
        ushort4 u = *(const ushort4*)(tg + ri * HW + g * 4);
        int h = g / 14, w4 = g - h * 14;
        Tb[(w4 * 4 + 0) * 136 + ri * 56 + h] = u.x;
        Tb[(w4 * 4 + 1) * 136 + ri * 56 + h] = u.y;
        Tb[(w4 * 4 + 2) * 136 + ri * 56 + h] = u.z;
        Tb[(w4 * 4 + 3) * 136 + ri * 56 + h] = u.w;
    }
    __syncthreads();

    // ---- Phase B: U = F * T ----
    {
        const int p  = wv >> 1;          // 0: U_r, 1: U_i
        const int mh = (wv & 1) * 2;     // m-tiles mh, mh+1
        float4a s1[2][4];
        #pragma unroll
        for (int mi = 0; mi < 2; ++mi)
            #pragma unroll
            for (int nt = 0; nt < 4; ++nt) s1[mi][nt] = (float4a){0.f, 0.f, 0.f, 0.f};
        #pragma unroll
        for (int ks = 0; ks < 4; ++ks) {
            short8 bfr[4];
            #pragma unroll
            for (int nt = 0; nt < 4; ++nt) {
                int row = nt * 16 + n; if (row > 55) row = 55;  // clamp: cols discarded
                bfr[nt] = *(const short8*)(Tb + row * 136 + ks * 32 + q * 8);
            }
            #pragma unroll
            for (int mi = 0; mi < 2; ++mi) {
                short8 afr = *(const short8*)(Ffix + ((((p * 4 + mh + mi) * 4 + ks) * 64 + lane) * 8));
                #pragma unroll
                for (int nt = 0; nt < 4; ++nt)
                    s1[mi][nt] = __builtin_amdgcn_mfma_f32_16x16x32_bf16(afr, bfr[nt], s1[mi][nt], 0, 0, 0);
            }
        }
        #pragma unroll
        for (int mi = 0; mi < 2; ++mi)
            #pragma unroll
            for (int nt = 0; nt < 4; ++nt)
                #pragma unroll
                for (int r = 0; r < 4; ++r) {
                    int kh = (mh + mi) * 16 + q * 4 + r;
                    int w  = nt * 16 + n;
                    if (kh < 56 && w < 56)
                        Ub[kh * 136 + p * 56 + w] = f2bf(s1[mi][nt][r]);
                }
    }
    __syncthreads();

    // ---- Phase C: G = U * F (wave wv owns kh-tile wv, both parts) ----
    const int mt = wv;
    short8 afr2[4];
    #pragma unroll
    for (int ks = 0; ks < 4; ++ks) {
        int row = mt * 16 + n; if (row > 55) row = 55;          // clamp: rows discarded
        afr2[ks] = *(const short8*)(Ub + row * 136 + ks * 32 + q * 8);
    }
    float4a g[2][4];
    #pragma unroll
    for (int pp = 0; pp < 2; ++pp)
        #pragma unroll
        for (int nt = 0; nt < 4; ++nt) g[pp][nt] = (float4a){0.f, 0.f, 0.f, 0.f};
    #pragma unroll
    for (int pp = 0; pp < 2; ++pp)
        #pragma unroll
        for (int ks = 0; ks < 4; ++ks)
            #pragma unroll
            for (int nt = 0; nt < 4; ++nt) {
                short8 bfr = *(const short8*)(Ffix + ((((pp * 4 + nt) * 4 + ks) * 64 + lane) * 8));
                g[pp][nt] = __builtin_amdgcn_mfma_f32_16x16x32_bf16(afr2[ks], bfr, g[pp][nt], 0, 0, 0);
            }

    // ---- Epilogue: fused magnitude + weighted sums vs global x ----
    const bool doflip = (lp >= 1 && lp <= 3);
    const float* x1 = x + ((size_t)((b * 8 + lp) * 64 + c)) * HW;
    const float* x2 = x + ((size_t)((b * 8 + ((8 - lp) & 7)) * 64 + c)) * HW;
    float S1 = 0.f, X1 = 0.f, S2 = 0.f, X2 = 0.f;
    #pragma unroll
    for (int nt = 0; nt < 4; ++nt) {
        int kw = nt * 16 + n;
        if (kw < 56) {
            int kwf = (56 - kw) % 56;
            #pragma unroll
            for (int r = 0; r < 4; ++r) {
                int kh = mt * 16 + q * 4 + r;
                if (kh < 56) {
                    float gr = g[0][nt][r], gi = g[1][nt][r];
                    float mag = sqrtf(gr * gr + gi * gi);
                    float v1 = x1[kh * 56 + kw];
                    S1 += mag * v1; X1 += v1;
                    if (doflip) {
                        int khf = (56 - kh) % 56;
                        float v2 = x2[khf * 56 + kwf];
                        S2 += mag * v2; X2 += v2;
                    }
                }
            }
        }
    }
    #pragma unroll
    for (int m = 1; m < 64; m <<= 1) {
        S1 += __shfl_xor(S1, m);
        X1 += __shfl_xor(X1, m);
        S2 += __shfl_xor(S2, m);
        X2 += __shfl_xor(X2, m);
    }
    if (lane == 0) { red[wv * 4 + 0] = S1; red[wv * 4 + 1] = X1;
                     red[wv * 4 + 2] = S2; red[wv * 4 + 3] = X2; }
    __syncthreads();
    if (tid == 0) {
        float s1 = 0.f, xs1 = 0.f, s2 = 0.f, xs2 = 0.f;
        #pragma unroll
        for (int w = 0; w < 4; ++w) {
            s1 += red[w * 4 + 0]; xs1 += red[w * 4 + 1];
            s2 += red[w * 4 + 2]; xs2 += red[w * 4 + 3];
        }
        const float kS = 0.01f / (56.0f * 2.8284271247461903f);
        pooled[bc * 8 + lp] = (xs1 + kS * s1) / 3136.0f;
        if (doflip)
            pooled[bc * 8 + (8 - lp)] = (xs2 + kS * s2) / 3136.0f;
    }
}

// ---------------------------------------------------------------------------
// Kernel 2: calib + fc
// ---------------------------------------------------------------------------
__global__ __launch_bounds__(64)
void calib_kernel(const float* __restrict__ pooled,
                  const float* __restrict__ tw_, const float* __restrict__ tb,
                  const float* __restrict__ fcw, const float* __restrict__ fcb,
                  const float* __restrict__ convb,
                  float* __restrict__ scale, float* __restrict__ fbias) {
    const int nn = blockIdx.x;
    const int b = nn >> 3, l = nn & 7;
    const int o = threadIdx.x;
    const float* pr = pooled + b * 512 + l;
    float dot = 0.f;
    #pragma unroll 8
    for (int c0 = 0; c0 < 64; ++c0) dot += tw_[o * 64 + c0] * pr[c0 * 8];
    float fcp = fcw[o] * pr[o * 8];
    #pragma unroll
    for (int off = 32; off > 0; off >>= 1) fcp += __shfl_down(fcp, off);
    float fcout = __shfl(fcp, 0) + fcb[0];
    scale[nn * 64 + o] = 1.0f + tb[o] + dot;
    fbias[nn * 64 + o] = convb[o] * (fcout + 1.0f);
}

// ---------------------------------------------------------------------------
// Kernel 3: conv as bf16 MFMA GEMM, 4-row tiles (46 KB LDS -> 3 blocks/CU).
// Wave wv owns px-tiles {wv+4k}; residual recovered from LDS bf16(x*s)/s.
// ---------------------------------------------------------------------------
__global__ __launch_bounds__(256, 3)
void conv_mfma_kernel(const float* __restrict__ x,
                      const unsigned short* __restrict__ Wp,
                      const float* __restrict__ scale, const float* __restrict__ fbias,
                      float* __restrict__ out,
                      float* __restrict__ psum, float* __restrict__ psum2) {
    const int rt = blockIdx.x;           // 0..13
    const int nn = blockIdx.y;           // 0..63
    const int tid  = threadIdx.x;
    const int lane = tid & 63;
    const int wv   = tid >> 6;
    const int r0   = rt * 4;

    __shared__ unsigned short xs[6 * 60 * 64];    // 46.08 KB
    __shared__ float fb[64], ssc[64], rsc[64], bn1[64], bn2[64];

    if (tid < 64) {
        fb[tid]  = fbias[nn * 64 + tid];
        float s  = scale[nn * 64 + tid];
        ssc[tid] = s;
        rsc[tid] = 1.0f / s;
        bn1[tid] = 0.f; bn2[tid] = 0.f;
    }
    __syncthreads();

    for (int t = tid; t < 6144; t += 256) {
        if (t < 5376) {                       // 64i x 6r x 14c4
            int c4 = t % 14;
            int rr = (t / 14) % 6;
            int i  = t / 84;
            int gr = r0 - 1 + rr;
            float4 v = make_float4(0.f, 0.f, 0.f, 0.f);
            if (gr >= 0 && gr < 56)
                v = *(const float4*)(x + ((size_t)(nn * 64 + i) * HW + gr * 56 + c4 * 4));
            float s = ssc[i];
            int gg = i >> 3, il = i & 7;
            float vv[4] = {v.x, v.y, v.z, v.w};
            #pragma unroll
            for (int j = 0; j < 4; ++j) {
                int lc = c4 * 4 + 1 + j;
                xs[(rr * 60 + lc) * 64 + (((gg ^ (lc & 7)) << 3) | il)] = f2bf(vv[j] * s);
            }
        } else {                              // halo cols: 64i x 6r x 2
            int idx = t - 5376;
            int i   = idx / 12;
            int rem = idx - i * 12;
            int rr  = rem >> 1;
            int lc  = (rem & 1) * 57;
            int gg = i >> 3, il = i & 7;
            xs[(rr * 60 + lc) * 64 + (((gg ^ (lc & 7)) << 3) | il)] = 0;
        }
    }
    __syncthreads();

    const int pxo = lane & 15;
    const int q   = lane >> 4;

    float4a acc[4][4];
    #pragma unroll
    for (int j = 0; j < 4; ++j)
        #pragma unroll
        for (int ot = 0; ot < 4; ++ot) acc[j][ot] = (float4a){0.f, 0.f, 0.f, 0.f};

    int rp[4], cp[4];
    bool vld[4];
    #pragma unroll
    for (int j = 0; j < 4; ++j) {
        int tl = wv + 4 * j;
        vld[j] = (tl < 14);
        if (tl > 13) tl = 13;                 // clamp: duplicate compute, stores skipped
        int px = tl * 16 + pxo;
        rp[j] = px / 56;
        cp[j] = px - rp[j] * 56;
    }

    #pragma unroll 1
    for (int kk = 0; kk < 9; ++kk) {
        const int dr = kk / 3, dc = kk - dr * 3;
        short8 a[4][2];
        #pragma unroll
        for (int ot = 0; ot < 4; ++ot)
            #pragma unroll
            for (int ih = 0; ih < 2; ++ih)
                a[ot][ih] = *(const short8*)(Wp + ((kk * 64 + ot * 16 + pxo) * 64 + ih * 32 + q * 8));

        #pragma unroll
        for (int j = 0; j < 4; ++j) {
            int lc = cp[j] + dc;
            int base = ((rp[j] + dr) * 60 + lc) * 64;
            int sw = lc & 7;
            #pragma unroll
            for (int ih = 0; ih < 2; ++ih) {
                short8 bv = *(const short8*)&xs[base + (((q + ih * 4) ^ sw) << 3)];
                #pragma unroll
                for (int ot = 0; ot < 4; ++ot)
                    acc[j][ot] = __builtin_amdgcn_mfma_f32_16x16x32_bf16(a[ot][ih], bv, acc[j][ot], 0, 0, 0);
            }
        }
    }

    float bs[4][4], bs2[4][4];
    #pragma unroll
    for (int ot = 0; ot < 4; ++ot)
        #pragma unroll
        for (int r = 0; r < 4; ++r) { bs[ot][r] = 0.f; bs2[ot][r] = 0.f; }

    #pragma unroll
    for (int j = 0; j < 4; ++j) {
        if (!vld[j]) continue;
        int px  = (wv + 4 * j) * 16 + pxo;
        int gpx = r0 * 56 + px;
        int rr  = rp[j] + 1;
        int lc  = cp[j] + 1;
        int sw  = lc & 7;
        int rowbase = (rr * 60 + lc) * 64;
        #pragma unroll
        for (int ot = 0; ot < 4; ++ot) {
            int gg = ot * 2 + (q >> 1);
            ushort4 uu = *(const ushort4*)(xs + rowbase + (((gg ^ sw) << 3) | ((q & 1) * 4)));
            float resid[4] = {bf2f(uu.x), bf2f(uu.y), bf2f(uu.z), bf2f(uu.w)};
            #pragma unroll
            for (int r = 0; r < 4; ++r) {
                int o = ot * 16 + q * 4 + r;
                size_t off = (size_t)(nn * 64 + o) * HW + gpx;
                float v = acc[j][ot][r] + resid[r] * rsc[o] + fb[o];
                out[off] = v;
                bs[ot][r]  += v;
                bs2[ot][r] += v * v;
            }
        }
    }
    #pragma unroll
    for (int ot = 0; ot < 4; ++ot)
        #pragma unroll
        for (int r = 0; r < 4; ++r) {
            #pragma unroll
            for (int m = 1; m < 16; m <<= 1) {
                bs[ot][r]  += __shfl_xor(bs[ot][r], m);
                bs2[ot][r] += __shfl_xor(bs2[ot][r], m);
            }
        }
    if (pxo == 0) {
        #pragma unroll
        for (int ot = 0; ot < 4; ++ot)
            #pragma unroll
            for (int r = 0; r < 4; ++r) {
                int o = ot * 16 + q * 4 + r;
                atomicAdd(&bn1[o], bs[ot][r]);
                atomicAdd(&bn2[o], bs2[ot][r]);
            }
    }
    __syncthreads();
    if (tid < 64) {
        int bl = nn * 14 + rt;
        psum[bl * 64 + tid]  = bn1[tid];
        psum2[bl * 64 + tid] = bn2[tid];
    }
}

// ---------------------------------------------------------------------------
// Kernel 4: reduce partials -> per-channel mean / invstd
// ---------------------------------------------------------------------------
__global__ __launch_bounds__(256)
void bnstat_kernel(const float* __restrict__ psum, const float* __restrict__ psum2,
                   float* __restrict__ bn) {
    const int o = blockIdx.x;
    const int tid = threadIdx.x;
    float s = 0.f, s2 = 0.f;
    for (int bl = tid; bl < NBLK3; bl += 256) {
        s  += psum[bl * 64 + o];
        s2 += psum2[bl * 64 + o];
    }
    __shared__ float r1[256], r2[256];
    r1[tid] = s; r2[tid] = s2;
    __syncthreads();
    for (int st = 128; st > 0; st >>= 1) {
        if (tid < st) { r1[tid] += r1[tid + st]; r2[tid] += r2[tid + st]; }
        __syncthreads();
    }
    if (tid == 0) {
        const float N = 64.0f * (float)HW;
        float mean = r1[0] / N;
        float var  = r2[0] / N - mean * mean;
        bn[o]      = mean;
        bn[64 + o] = rsqrtf(var + 1e-5f);
    }
}

// ---------------------------------------------------------------------------
// Kernel 5: BN + SiLU in place
// ---------------------------------------------------------------------------
__global__ __launch_bounds__(256)
void bnsilu_kernel(float* __restrict__ out, const float* __restrict__ bn,
                   const float* __restrict__ gamma, const float* __restrict__ beta) {
    size_t idx = (size_t)blockIdx.x * 256 + threadIdx.x;
    if (idx >= (size_t)NF * 64 * HW) return;
    int c = (int)((idx / HW) & 63);
    float v = out[idx];
    float y = (v - bn[c]) * bn[64 + c] * gamma[c] + beta[c];
    out[idx] = y / (1.0f + expf(-y));
}

extern "C" void kernel_launch(void* const* d_in, const int* in_sizes, int n_in,
                              void* d_out, int out_size, void* d_ws, size_t ws_size,
                              hipStream_t stream) {
    const float* x          = (const float*)d_in[0];
    const float* temporal_w = (const float*)d_in[1];
    const float* temporal_b = (const float*)d_in[2];
    const float* fc_w       = (const float*)d_in[3];
    const float* fc_b       = (const float*)d_in[4];
    const float* conv_w     = (const float*)d_in[5];
    const float* conv_b     = (const float*)d_in[6];
    const float* bn_gamma   = (const float*)d_in[7];
    const float* bn_beta    = (const float*)d_in[8];
    float* out = (float*)d_out;
    float* ws  = (float*)d_ws;

    float* pooled = ws;                               // 4096 f
    float* scale  = ws + 4096;                        // 4096 f
    float* fbias  = ws + 8192;                        // 4096 f
    unsigned short* Wp = (unsigned short*)(ws + 12288);   // 36864 us = 18432 f
    float* psum   = ws + 12288 + 18432;               // 896*64 f
    float* psum2  = psum + NBLK3 * 64;                // 896*64 f
    float* bn     = psum2 + NBLK3 * 64;               // 128 f
    unsigned short* Ffix = (unsigned short*)(bn + 128);   // 16384 us

    // T planes (bf16, 32 MB) live in d_out (51 MB) until conv overwrites it.
    unsigned short* Tg = (unsigned short*)d_out;

    pack_kernel<<<208, 256, 0, stream>>>(conv_w, Ffix, Wp);
    tdft_kernel<<<1024, 256, 0, stream>>>(x, Tg);
    fft2_kernel<<<2560, 256, 0, stream>>>(x, Tg, Ffix, pooled);
    calib_kernel<<<64, 64, 0, stream>>>(pooled, temporal_w, temporal_b,
                                        fc_w, fc_b, conv_b, scale, fbias);
    conv_mfma_kernel<<<dim3(14, 64), 256, 0, stream>>>(x, Wp, scale, fbias,
                                                       out, psum, psum2);
    bnstat_kernel<<<64, 256, 0, stream>>>(psum, psum2, bn);
    int total = NF * 64 * HW;
    bnsilu_kernel<<<(total + 255) / 256, 256, 0, stream>>>(out, bn, bn_gamma, bn_beta);
}

// Round 7
// 240.750 us; speedup vs baseline: 1.0837x; 1.0837x over previous
//
#include <hip/hip_runtime.h>
#include <cmath>

#define HW 3136          // 56*56
#define NF 64            // BB*LL frames
#define NBLK2 448        // NF * 7 row-tiles (conv blocks)

typedef __attribute__((ext_vector_type(8))) short short8;
typedef __attribute__((ext_vector_type(4))) float float4a;

__device__ __forceinline__ unsigned short f2bf(float f) {
    unsigned int u = __float_as_uint(f);
    u += 0x7fffu + ((u >> 16) & 1u);   // RNE
    return (unsigned short)(u >> 16);
}
__device__ __forceinline__ float bf2f(unsigned short u) {
    return __uint_as_float(((unsigned int)u) << 16);
}

// cos/sin of -2*pi*k/8 for k=0..7
__device__ __constant__ float TW8C[8] = {1.f, 0.70710678f, 0.f, -0.70710678f, -1.f, -0.70710678f, 0.f, 0.70710678f};
__device__ __constant__ float TW8S[8] = {0.f, -0.70710678f, -1.f, -0.70710678f, 0.f, 0.70710678f, 1.f, 0.70710678f};

// ---------------------------------------------------------------------------
// Kernel 0: pack DFT matrix (blocks 0..63) + repack conv_w (blocks 64..207).
// Ffix[p][t][ks][lane][j]: Astack_p[t*16+(lane&15)][ks*32+(lane>>4)*8+j]
//   Astack_0 = [Fr | -Fi] (K=112 pad 128), Astack_1 = [Fi | Fr]
// F symmetric => serves as A-frag (stage1, m-rows) AND B-frag (stage2, n-cols).
// Wp[kk][o][i] bf16 from conv_w[o][i][kk] fp32.
// ---------------------------------------------------------------------------
__global__ __launch_bounds__(256)
void pack_kernel(const float* __restrict__ cw,
                 unsigned short* __restrict__ Ffix,
                 unsigned short* __restrict__ Wp) {
    if (blockIdx.x < 64) {
        int idx = blockIdx.x * 256 + threadIdx.x;    // 16384
        int j    = idx & 7;
        int lane = (idx >> 3) & 63;
        int ks   = (idx >> 9) & 3;
        int t    = (idx >> 11) & 3;
        int p    = (idx >> 13) & 1;
        int mn = t * 16 + (lane & 15);
        int k  = ks * 32 + (lane >> 4) * 8 + j;
        float val = 0.f;
        if (mn < 56 && k < 112) {
            int kk = (k < 56) ? k : k - 56;
            int prod = (mn * kk) % 56;
            float ang = -6.2831853071795864f * (float)prod / 56.0f;
            float cr = cosf(ang);
            float ci = sinf(ang);
            float first  = (p == 0) ? cr : ci;
            float second = (p == 0) ? -ci : cr;
            val = (k < 56) ? first : second;
        }
        Ffix[idx] = f2bf(val);
    } else {
        int idx = (blockIdx.x - 64) * 256 + threadIdx.x;
        if (idx < 36864) {
            int i  = idx & 63;
            int o  = (idx >> 6) & 63;
            int kk = idx >> 12;
            Wp[idx] = f2bf(cw[(o * 64 + i) * 9 + kk]);
        }
    }
}

// ---------------------------------------------------------------------------
// Kernel 1a: temporal DFT for ALL lp=0..4 in one streaming pass.
// Reads x[b,:,c,chunk] once, writes bf16 planes
// Tg[((bc)*5+lp)*2+ri][3136] (h-major; Tg lives in d_out scratch).
// ---------------------------------------------------------------------------
__global__ __launch_bounds__(256)
void tdft_kernel(const float* __restrict__ x, unsigned short* __restrict__ Tg) {
    const int chunk = blockIdx.x & 1;
    const int bc    = blockIdx.x >> 1;     // 512
    const int c     = bc & 63;
    const int b     = bc >> 6;
    const int tid   = threadIdx.x;

    const float* xb = x + ((size_t)(b * 512 + c)) * HW;   // stride per l: 64*HW

    for (int g = chunk * 392 + tid; g < (chunk + 1) * 392; g += 256) {
        float4 v[8];
        #pragma unroll
        for (int l = 0; l < 8; ++l)
            v[l] = *(const float4*)(xb + (size_t)l * 64 * HW + g * 4);
        #pragma unroll
        for (int lp = 0; lp < 5; ++lp) {
            float re[4] = {0.f, 0.f, 0.f, 0.f}, im[4] = {0.f, 0.f, 0.f, 0.f};
            #pragma unroll
            for (int l = 0; l < 8; ++l) {
                float tr = TW8C[(l * lp) & 7], ti = TW8S[(l * lp) & 7];
                re[0] += v[l].x * tr; im[0] += v[l].x * ti;
                re[1] += v[l].y * tr; im[1] += v[l].y * ti;
                re[2] += v[l].z * tr; im[2] += v[l].z * ti;
                re[3] += v[l].w * tr; im[3] += v[l].w * ti;
            }
            ushort4 ur, ui;
            ur.x = f2bf(re[0]); ur.y = f2bf(re[1]); ur.z = f2bf(re[2]); ur.w = f2bf(re[3]);
            ui.x = f2bf(im[0]); ui.y = f2bf(im[1]); ui.z = f2bf(im[2]); ui.w = f2bf(im[3]);
            size_t base = ((size_t)(bc * 5 + lp) * 2) * HW + g * 4;
            *(ushort4*)(Tg + base)      = ur;
            *(ushort4*)(Tg + base + HW) = ui;
        }
    }
}

// ---------------------------------------------------------------------------
// Kernel 1b: channel-batched 2D DFT via MFMA + fused |G| pooling.
// Block = (b, lp, 2-channel chunk): 1280 blocks.
//  Stage 1: U_p[kh][(ci,w)] = Astack_p[56x112] x Tstack[112 x 112]   (batched N)
//  Stage 2: G_p[(ci,kh)][kw] = A2[(ci,kh) x 112] x Bstack_p[112 x 56] (batched M)
// Single LDS buffer AB[112][136]: holds Tstack (B-operand), then U (A-operand).
// ---------------------------------------------------------------------------
__global__ __launch_bounds__(256)
void fft2b_kernel(const float* __restrict__ x,
                  const unsigned short* __restrict__ Tg,
                  const unsigned short* __restrict__ Ffix,
                  float* __restrict__ pooled) {
    const int bid = blockIdx.x;          // 1280 = (b*5+lp)*32 + ch
    const int ch  = bid & 31;
    const int rem = bid >> 5;
    const int lp  = rem % 5;
    const int b   = rem / 5;
    const int c0  = ch * 2;
    const int tid  = threadIdx.x;
    const int lane = tid & 63;
    const int wv   = tid >> 6;
    const int n16  = lane & 15;
    const int q    = lane >> 4;

    __shared__ unsigned short AB[112 * 136];     // 30464 B
    __shared__ float pacc[2][4];                 // [ci][S1,X1,S2,X2]

    if (tid < 8) ((float*)pacc)[tid] = 0.f;
    // zero K-pad (k=112..135) for all 112 rows
    for (int t = tid; t < 1344; t += 256) {
        int row = t / 12, kk2 = t - row * 12;
        *(unsigned int*)&AB[row * 136 + 112 + kk2 * 2] = 0u;
    }
    // stage Tstack: AB[(ci*56+w)][ri*56+h] from Tg planes (h-major)
    for (int t = tid; t < 3136; t += 256) {      // ci(2) x ri(2) x 784 u4-groups
        int ci = t / 1568;                       // FIXED (was t>>11: left LDS rows unwritten -> NaN)
        int r2 = t - ci * 1568;
        int ri = r2 / 784, g = r2 - ri * 784;
        size_t plane = ((size_t)((b * 64 + c0 + ci) * 5 + lp) * 2 + ri) * HW;
        ushort4 u = *(const ushort4*)(Tg + plane + g * 4);
        int h = g / 14, w4 = g - h * 14;
        int base = (ci * 56 + w4 * 4) * 136 + ri * 56 + h;
        AB[base]           = u.x;
        AB[base + 136]     = u.y;
        AB[base + 272]     = u.z;
        AB[base + 408]     = u.w;
    }
    __syncthreads();

    // ---- Stage 1: wave = (p = wv>>1, m-tiles mh2,mh2+1) ----
    const int p   = wv >> 1;
    const int mh2 = (wv & 1) * 2;
    float4a s1[2][7];
    #pragma unroll
    for (int mi = 0; mi < 2; ++mi)
        #pragma unroll
        for (int nt = 0; nt < 7; ++nt) s1[mi][nt] = (float4a){0.f, 0.f, 0.f, 0.f};
    #pragma unroll
    for (int ks = 0; ks < 4; ++ks) {
        short8 bfr[7];
        #pragma unroll
        for (int nt = 0; nt < 7; ++nt)
            bfr[nt] = *(const short8*)&AB[(nt * 16 + n16) * 136 + ks * 32 + q * 8];
        #pragma unroll
        for (int mi = 0; mi < 2; ++mi) {
            short8 afr = *(const short8*)(Ffix + ((((p * 4 + mh2 + mi) * 4 + ks) * 64 + lane) * 8));
            #pragma unroll
            for (int nt = 0; nt < 7; ++nt)
                s1[mi][nt] = __builtin_amdgcn_mfma_f32_16x16x32_bf16(afr, bfr[nt], s1[mi][nt], 0, 0, 0);
        }
    }
    __syncthreads();   // all Tstack reads done; safe to overwrite with U

    // write U -> AB as A2[m=(ci*56+kh)][k=p*56+w]
    #pragma unroll
    for (int mi = 0; mi < 2; ++mi)
        #pragma unroll
        for (int nt = 0; nt < 7; ++nt)
            #pragma unroll
            for (int r = 0; r < 4; ++r) {
                int kh = (mh2 + mi) * 16 + q * 4 + r;
                if (kh < 56) {
                    int nidx = nt * 16 + n16;
                    int ci = (nidx >= 56) ? 1 : 0;
                    int w  = nidx - ci * 56;
                    AB[(ci * 56 + kh) * 136 + p * 56 + w] = f2bf(s1[mi][nt][r]);
                }
            }
    __syncthreads();

    // ---- Stage 2 + epilogue: units mt2 in {wv, wv+4} ----
    const bool doflip = (lp >= 1 && lp <= 3);
    const float* x1a = x + ((size_t)((b * 8 + lp) * 64 + c0)) * HW;
    const float* x1b = x1a + HW;
    const float* x2a = x + ((size_t)((b * 8 + ((8 - lp) & 7)) * 64 + c0)) * HW;
    const float* x2b = x2a + HW;
    float Sa = 0.f, Xa = 0.f, Sb = 0.f, Xb = 0.f;
    float S2a = 0.f, X2a = 0.f, S2b = 0.f, X2b = 0.f;

    #pragma unroll
    for (int ui = 0; ui < 2; ++ui) {
        int mt2 = wv + ui * 4;
        if (mt2 > 6) continue;
        short8 afr2[4];
        #pragma unroll
        for (int ks = 0; ks < 4; ++ks)
            afr2[ks] = *(const short8*)&AB[(mt2 * 16 + n16) * 136 + ks * 32 + q * 8];
        float4a gr[4], gi[4];
        #pragma unroll
        for (int nt = 0; nt < 4; ++nt) { gr[nt] = (float4a){0.f,0.f,0.f,0.f}; gi[nt] = (float4a){0.f,0.f,0.f,0.f}; }
        #pragma unroll
        for (int ks = 0; ks < 4; ++ks)
            #pragma unroll
            for (int nt = 0; nt < 4; ++nt) {
                short8 b0 = *(const short8*)(Ffix + (((nt * 4 + ks) * 64 + lane) * 8));
                short8 b1 = *(const short8*)(Ffix + ((((4 + nt) * 4 + ks) * 64 + lane) * 8));
                gr[nt] = __builtin_amdgcn_mfma_f32_16x16x32_bf16(afr2[ks], b0, gr[nt], 0, 0, 0);
                gi[nt] = __builtin_amdgcn_mfma_f32_16x16x32_bf16(afr2[ks], b1, gi[nt], 0, 0, 0);
            }
        // epilogue for this unit
        #pragma unroll
        for (int nt = 0; nt < 4; ++nt) {
            int kw = nt * 16 + n16;
            if (kw < 56) {
                int kwf = (56 - kw) % 56;
                #pragma unroll
                for (int r = 0; r < 4; ++r) {
                    int m  = mt2 * 16 + q * 4 + r;
                    int ci = (m >= 56) ? 1 : 0;
                    int kh = m - ci * 56;
                    float grv = gr[nt][r], giv = gi[nt][r];
                    float mag = sqrtf(grv * grv + giv * giv);
                    const float* xp1 = ci ? x1b : x1a;
                    float v1 = xp1[kh * 56 + kw];
                    if (ci) { Sb += mag * v1; Xb += v1; }
                    else    { Sa += mag * v1; Xa += v1; }
                    if (doflip) {
                        int khf = (56 - kh) % 56;
                        const float* xp2 = ci ? x2b : x2a;
                        float v2 = xp2[khf * 56 + kwf];
                        if (ci) { S2b += mag * v2; X2b += v2; }
                        else    { S2a += mag * v2; X2a += v2; }
                    }
                }
            }
        }
    }
    #pragma unroll
    for (int m = 1; m < 64; m <<= 1) {
        Sa += __shfl_xor(Sa, m);   Xa += __shfl_xor(Xa, m);
        Sb += __shfl_xor(Sb, m);   Xb += __shfl_xor(Xb, m);
        S2a += __shfl_xor(S2a, m); X2a += __shfl_xor(X2a, m);
        S2b += __shfl_xor(S2b, m); X2b += __shfl_xor(X2b, m);
    }
    if (lane == 0) {
        atomicAdd(&pacc[0][0], Sa);  atomicAdd(&pacc[0][1], Xa);
        atomicAdd(&pacc[1][0], Sb);  atomicAdd(&pacc[1][1], Xb);
        atomicAdd(&pacc[0][2], S2a); atomicAdd(&pacc[0][3], X2a);
        atomicAdd(&pacc[1][2], S2b); atomicAdd(&pacc[1][3], X2b);
    }
    __syncthreads();
    if (tid < 2) {
        const float kS = 0.01f / (56.0f * 2.8284271247461903f);
        int c = c0 + tid;
        pooled[(b * 64 + c) * 8 + lp] = (pacc[tid][1] + kS * pacc[tid][0]) / 3136.0f;
        if (doflip)
            pooled[(b * 64 + c) * 8 + (8 - lp)] = (pacc[tid][3] + kS * pacc[tid][2]) / 3136.0f;
    }
}

// ---------------------------------------------------------------------------
// Kernel 2: calib + fc
// ---------------------------------------------------------------------------
__global__ __launch_bounds__(64)
void calib_kernel(const float* __restrict__ pooled,
                  const float* __restrict__ tw_, const float* __restrict__ tb,
                  const float* __restrict__ fcw, const float* __restrict__ fcb,
                  const float* __restrict__ convb,
                  float* __restrict__ scale, float* __restrict__ fbias) {
    const int nn = blockIdx.x;
    const int b = nn >> 3, l = nn & 7;
    const int o = threadIdx.x;
    const float* pr = pooled + b * 512 + l;
    float dot = 0.f;
    #pragma unroll 8
    for (int c0 = 0; c0 < 64; ++c0) dot += tw_[o * 64 + c0] * pr[c0 * 8];
    float fcp = fcw[o] * pr[o * 8];
    #pragma unroll
    for (int off = 32; off > 0; off >>= 1) fcp += __shfl_down(fcp, off);
    float fcout = __shfl(fcp, 0) + fcb[0];
    scale[nn * 64 + o] = 1.0f + tb[o] + dot;
    fbias[nn * 64 + o] = convb[o] * (fcout + 1.0f);
}

// ---------------------------------------------------------------------------
// Kernel 3: conv as bf16 MFMA GEMM (round-4 version: 8-row tiles, 2 blk/CU).
// Residual recovered from LDS bf16(x*s)/s.
// ---------------------------------------------------------------------------
__global__ __launch_bounds__(256, 2)
void conv_mfma_kernel(const float* __restrict__ x,
                      const unsigned short* __restrict__ Wp,
                      const float* __restrict__ scale, const float* __restrict__ fbias,
                      float* __restrict__ out,
                      float* __restrict__ psum, float* __restrict__ psum2) {
    const int rt = blockIdx.x;
    const int nn = blockIdx.y;
    const int tid  = threadIdx.x;
    const int lane = tid & 63;
    const int wv   = tid >> 6;
    const int r0   = rt * 8;

    __shared__ unsigned short xs[10 * 60 * 64];   // 76.8 KB
    __shared__ float fb[64], ssc[64], rsc[64], bn1[64], bn2[64];

    if (tid < 64) {
        fb[tid]  = fbias[nn * 64 + tid];
        float s  = scale[nn * 64 + tid];
        ssc[tid] = s;
        rsc[tid] = 1.0f / s;
        bn1[tid] = 0.f; bn2[tid] = 0.f;
    }
    __syncthreads();

    for (int t = tid; t < 10240; t += 256) {
        if (t < 8960) {
            int c4 = t % 14;
            int rr = (t / 14) % 10;
            int i  = t / 140;
            int gr = r0 - 1 + rr;
            float4 v = make_float4(0.f, 0.f, 0.f, 0.f);
            if (gr >= 0 && gr < 56)
                v = *(const float4*)(x + ((size_t)(nn * 64 + i) * HW + gr * 56 + c4 * 4));
            float s = ssc[i];
            int g = i >> 3, il = i & 7;
            float vv[4] = {v.x, v.y, v.z, v.w};
            #pragma unroll
            for (int j = 0; j < 4; ++j) {
                int lc = c4 * 4 + 1 + j;
                xs[(rr * 60 + lc) * 64 + (((g ^ (lc & 7)) << 3) | il)] = f2bf(vv[j] * s);
            }
        } else {
            int idx = t - 8960;
            int i   = idx / 20;
            int rem = idx - i * 20;
            int rr  = rem >> 1;
            int lc  = (rem & 1) * 57;
            int g = i >> 3, il = i & 7;
            xs[(rr * 60 + lc) * 64 + (((g ^ (lc & 7)) << 3) | il)] = 0;
        }
    }
    __syncthreads();

    const int pxo = lane & 15;
    const int q   = lane >> 4;

    float4a acc[7][4];
    #pragma unroll
    for (int j = 0; j < 7; ++j)
        #pragma unroll
        for (int ot = 0; ot < 4; ++ot) acc[j][ot] = (float4a){0.f, 0.f, 0.f, 0.f};

    int rp[7], cp[7];
    #pragma unroll
    for (int j = 0; j < 7; ++j) {
        int px = (wv * 7 + j) * 16 + pxo;
        rp[j] = px / 56;
        cp[j] = px - rp[j] * 56;
    }

    #pragma unroll 1
    for (int kk = 0; kk < 9; ++kk) {
        const int dr = kk / 3, dc = kk - dr * 3;
        short8 a[4][2];
        #pragma unroll
        for (int ot = 0; ot < 4; ++ot)
            #pragma unroll
            for (int ih = 0; ih < 2; ++ih)
                a[ot][ih] = *(const short8*)(Wp + ((kk * 64 + ot * 16 + pxo) * 64 + ih * 32 + q * 8));

        #pragma unroll
        for (int j = 0; j < 7; ++j) {
            int lc = cp[j] + dc;
            int base = ((rp[j] + dr) * 60 + lc) * 64;
            int sw = lc & 7;
            #pragma unroll
            for (int ih = 0; ih < 2; ++ih) {
                short8 bv = *(const short8*)&xs[base + (((q + ih * 4) ^ sw) << 3)];
                #pragma unroll
                for (int ot = 0; ot < 4; ++ot)
                    acc[j][ot] = __builtin_amdgcn_mfma_f32_16x16x32_bf16(a[ot][ih], bv, acc[j][ot], 0, 0, 0);
            }
        }
    }

    float bs[4][4], bs2[4][4];
    #pragma unroll
    for (int ot = 0; ot < 4; ++ot)
        #pragma unroll
        for (int r = 0; r < 4; ++r) { bs[ot][r] = 0.f; bs2[ot][r] = 0.f; }

    #pragma unroll
    for (int j = 0; j < 7; ++j) {
        int px  = (wv * 7 + j) * 16 + pxo;
        int gpx = r0 * 56 + px;
        int rr  = rp[j] + 1;
        int lc  = cp[j] + 1;
        int sw  = lc & 7;
        int rowbase = (rr * 60 + lc) * 64;
        #pragma unroll
        for (int ot = 0; ot < 4; ++ot) {
            int g  = ot * 2 + (q >> 1);
            ushort4 uu = *(const ushort4*)(xs + rowbase + (((g ^ sw) << 3) | ((q & 1) * 4)));
            float resid[4] = {bf2f(uu.x), bf2f(uu.y), bf2f(uu.z), bf2f(uu.w)};
            #pragma unroll
            for (int r = 0; r < 4; ++r) {
                int o = ot * 16 + q * 4 + r;
                size_t off = (size_t)(nn * 64 + o) * HW + gpx;
                float v = acc[j][ot][r] + resid[r] * rsc[o] + fb[o];
                out[off] = v;
                bs[ot][r]  += v;
                bs2[ot][r] += v * v;
            }
        }
    }
    #pragma unroll
    for (int ot = 0; ot < 4; ++ot)
        #pragma unroll
        for (int r = 0; r < 4; ++r) {
            #pragma unroll
            for (int m = 1; m < 16; m <<= 1) {
                bs[ot][r]  += __shfl_xor(bs[ot][r], m);
                bs2[ot][r] += __shfl_xor(bs2[ot][r], m);
            }
        }
    if (pxo == 0) {
        #pragma unroll
        for (int ot = 0; ot < 4; ++ot)
            #pragma unroll
            for (int r = 0; r < 4; ++r) {
                int o = ot * 16 + q * 4 + r;
                atomicAdd(&bn1[o], bs[ot][r]);
                atomicAdd(&bn2[o], bs2[ot][r]);
            }
    }
    __syncthreads();
    if (tid < 64) {
        int bl = nn * 7 + rt;
        psum[bl * 64 + tid]  = bn1[tid];
        psum2[bl * 64 + tid] = bn2[tid];
    }
}

// ---------------------------------------------------------------------------
// Kernel 4: reduce partials -> per-channel mean / invstd
// ---------------------------------------------------------------------------
__global__ __launch_bounds__(256)
void bnstat_kernel(const float* __restrict__ psum, const float* __restrict__ psum2,
                   float* __restrict__ bn) {
    const int o = blockIdx.x;
    const int tid = threadIdx.x;
    float s = 0.f, s2 = 0.f;
    for (int bl = tid; bl < NBLK2; bl += 256) {
        s  += psum[bl * 64 + o];
        s2 += psum2[bl * 64 + o];
    }
    __shared__ float r1[256], r2[256];
    r1[tid] = s; r2[tid] = s2;
    __syncthreads();
    for (int st = 128; st > 0; st >>= 1) {
        if (tid < st) { r1[tid] += r1[tid + st]; r2[tid] += r2[tid + st]; }
        __syncthreads();
    }
    if (tid == 0) {
        const float N = 64.0f * (float)HW;
        float mean = r1[0] / N;
        float var  = r2[0] / N - mean * mean;
        bn[o]      = mean;
        bn[64 + o] = rsqrtf(var + 1e-5f);
    }
}

// ---------------------------------------------------------------------------
// Kernel 5: BN + SiLU in place
// ---------------------------------------------------------------------------
__global__ __launch_bounds__(256)
void bnsilu_kernel(float* __restrict__ out, const float* __restrict__ bn,
                   const float* __restrict__ gamma, const float* __restrict__ beta) {
    size_t idx = (size_t)blockIdx.x * 256 + threadIdx.x;
    if (idx >= (size_t)NF * 64 * HW) return;
    int c = (int)((idx / HW) & 63);
    float v = out[idx];
    float y = (v - bn[c]) * bn[64 + c] * gamma[c] + beta[c];
    out[idx] = y / (1.0f + expf(-y));
}

extern "C" void kernel_launch(void* const* d_in, const int* in_sizes, int n_in,
                              void* d_out, int out_size, void* d_ws, size_t ws_size,
                              hipStream_t stream) {
    const float* x          = (const float*)d_in[0];
    const float* temporal_w = (const float*)d_in[1];
    const float* temporal_b = (const float*)d_in[2];
    const float* fc_w       = (const float*)d_in[3];
    const float* fc_b       = (const float*)d_in[4];
    const float* conv_w     = (const float*)d_in[5];
    const float* conv_b     = (const float*)d_in[6];
    const float* bn_gamma   = (const float*)d_in[7];
    const float* bn_beta    = (const float*)d_in[8];
    float* out = (float*)d_out;
    float* ws  = (float*)d_ws;

    float* pooled = ws;                               // 4096 f
    float* scale  = ws + 4096;                        // 4096 f
    float* fbias  = ws + 8192;                        // 4096 f
    unsigned short* Wp = (unsigned short*)(ws + 12288);   // 36864 us = 18432 f
    float* psum   = ws + 12288 + 18432;               // 448*64 f
    float* psum2  = psum + NBLK2 * 64;                // 448*64 f
    float* bn     = psum2 + NBLK2 * 64;               // 128 f
    unsigned short* Ffix = (unsigned short*)(bn + 128);   // 16384 us

    // T planes (bf16, 32 MB) live in d_out (51 MB) until conv overwrites it.
    unsigned short* Tg = (unsigned short*)d_out;

    pack_kernel<<<208, 256, 0, stream>>>(conv_w, Ffix, Wp);
    tdft_kernel<<<1024, 256, 0, stream>>>(x, Tg);
    fft2b_kernel<<<1280, 256, 0, stream>>>(x, Tg, Ffix, pooled);
    calib_kernel<<<64, 64, 0, stream>>>(pooled, temporal_w, temporal_b,
                                        fc_w, fc_b, conv_b, scale, fbias);
    conv_mfma_kernel<<<dim3(7, 64), 256, 0, stream>>>(x, Wp, scale, fbias,
                                                      out, psum, psum2);
    bnstat_kernel<<<64, 256, 0, stream>>>(psum, psum2, bn);
    int total = NF * 64 * HW;
    bnsilu_kernel<<<(total + 255) / 256, 256, 0, stream>>>(out, bn, bn_gamma, bn_beta);
}